// Round 1
// baseline (197.991 us; speedup 1.0000x reference)
//
#include <hip/hip_runtime.h>
#include <hip/hip_bf16.h>
#include <math.h>

#define LSEQ 32768
#define DMODEL 256
#define DHID 256
#define NCH 512                 // concatenated [re|im] hidden channels
#define CHUNK 128
#define NCHUNKS (LSEQ / CHUNK)  // 256

typedef __bf16 bf16_t;
typedef __bf16 bf16x8 __attribute__((ext_vector_type(8)));
typedef __bf16 bf16x4 __attribute__((ext_vector_type(4)));
typedef float f32x4 __attribute__((ext_vector_type(4)));

__device__ __forceinline__ void async_load16(const void* g, void* l) {
  __builtin_amdgcn_global_load_lds((__attribute__((address_space(1))) void*)g,
                                   (__attribute__((address_space(3))) void*)l,
                                   16, 0, 0);
}

// ---------------- prep: lambda and lambda^CHUNK (fp64 for phase accuracy) ----
__global__ void prep_params(const float* __restrict__ nu_log,
                            const float* __restrict__ theta_log,
                            float* __restrict__ lam /* [4*DHID] */) {
  int h = threadIdx.x;
  if (h < DHID) {
    double nu = exp((double)nu_log[h]);
    double th = exp((double)theta_log[h]);
    double mag = exp(-nu);
    lam[h]            = (float)(mag * cos(th));
    lam[DHID + h]     = (float)(mag * sin(th));
    double magC = exp(-(double)CHUNK * nu);
    double phC  = fmod((double)CHUNK * th, 6.283185307179586);
    lam[2 * DHID + h] = (float)(magC * cos(phC));
    lam[3 * DHID + h] = (float)(magC * sin(phC));
  }
}

// W1[n][k], n in [0,512): n<256 -> B_re[n][k]*gamma[n]; else B_im[n-256][k]*gamma
__global__ void pack_w1(const float* __restrict__ B_re, const float* __restrict__ B_im,
                        const float* __restrict__ gamma_log, bf16_t* __restrict__ W1) {
  int n = blockIdx.x, k = threadIdx.x;
  int h = n & 255;
  float g = expf(gamma_log[h]);
  float v = (n < 256 ? B_re[h * DMODEL + k] : B_im[h * DMODEL + k]) * g;
  W1[n * DMODEL + k] = (bf16_t)v;
}

// W2[m][k], k in [0,512): k<256 -> C_re[m][k]; else -C_im[m][k-256]
__global__ void pack_w2(const float* __restrict__ C_re, const float* __restrict__ C_im,
                        bf16_t* __restrict__ W2) {
  int m = blockIdx.x, k = threadIdx.x;  // 512 threads
  float v = (k < 256) ? C_re[m * DHID + k] : -C_im[m * DHID + (k - 256)];
  W2[m * NCH + k] = (bf16_t)v;
}

__global__ void convert_x(const float* __restrict__ x, bf16_t* __restrict__ xb) {
  int i = blockIdx.x * 256 + threadIdx.x;
  float4 v = ((const float4*)x)[i];
  bf16x4 o = {(bf16_t)v.x, (bf16_t)v.y, (bf16_t)v.z, (bf16_t)v.w};
  ((bf16x4*)xb)[i] = o;
}

// ---------------- bf16 NT GEMM: C[L x N] = A[L x K] * Bw[N x K]^T ------------
// 128x128 block tile, BK=32, 4 waves in 2x2, each wave 4x4 of 16x16x32 MFMA.
__global__ __launch_bounds__(256) void gemm_bt(
    const bf16_t* __restrict__ A, const bf16_t* __restrict__ Bw,
    float* __restrict__ C, int K, int N,
    const float* __restrict__ X, const float* __restrict__ Dv, int fuse) {
  __shared__ __align__(16) bf16_t As[128 * 32];
  __shared__ __align__(16) bf16_t Bs[128 * 32];
  const int tid = threadIdx.x;
  const int r0 = blockIdx.y * 128;
  const int c0 = blockIdx.x * 128;
  const int wave = tid >> 6, lane = tid & 63;
  const int wm = wave & 1, wn = wave >> 1;
  const int lrow = lane & 15, lk = lane >> 4;

  f32x4 acc[4][4] = {};

  const int s0 = tid, s1 = tid + 256;
  const int r_s0 = s0 >> 2, k_s0 = (s0 & 3) * 8;
  const int r_s1 = s1 >> 2, k_s1 = (s1 & 3) * 8;

  for (int k0 = 0; k0 < K; k0 += 32) {
    __syncthreads();
    async_load16(A + (size_t)(r0 + r_s0) * K + k0 + k_s0, As + s0 * 8);
    async_load16(A + (size_t)(r0 + r_s1) * K + k0 + k_s1, As + s1 * 8);
    async_load16(Bw + (size_t)(c0 + r_s0) * K + k0 + k_s0, Bs + s0 * 8);
    async_load16(Bw + (size_t)(c0 + r_s1) * K + k0 + k_s1, Bs + s1 * 8);
    __syncthreads();
    bf16x8 af[4], bfr[4];
#pragma unroll
    for (int i = 0; i < 4; ++i)
      af[i] = *(const bf16x8*)(As + (wm * 64 + i * 16 + lrow) * 32 + lk * 8);
#pragma unroll
    for (int j = 0; j < 4; ++j)
      bfr[j] = *(const bf16x8*)(Bs + (wn * 64 + j * 16 + lrow) * 32 + lk * 8);
#pragma unroll
    for (int i = 0; i < 4; ++i)
#pragma unroll
      for (int j = 0; j < 4; ++j)
        acc[i][j] = __builtin_amdgcn_mfma_f32_16x16x32_bf16(af[i], bfr[j], acc[i][j], 0, 0, 0);
  }

#pragma unroll
  for (int i = 0; i < 4; ++i) {
#pragma unroll
    for (int r = 0; r < 4; ++r) {
      int row = r0 + wm * 64 + i * 16 + lk * 4 + r;
#pragma unroll
      for (int j = 0; j < 4; ++j) {
        int col = c0 + wn * 64 + j * 16 + lrow;
        float v = acc[i][j][r];
        if (fuse) v += X[(size_t)row * DMODEL + col] * Dv[col];
        C[(size_t)row * N + col] = v;
      }
    }
  }
}

// ---------------- scan pass 1: per-chunk local end state E_c -----------------
__global__ void scan_pass1(const float* __restrict__ Bu, const float* __restrict__ lam,
                           float* __restrict__ E) {
  int c = blockIdx.x, h = threadIdx.x;
  float lre = lam[h], lim = lam[DHID + h];
  float sre = 0.f, sim = 0.f;
  const float* p = Bu + (size_t)c * CHUNK * NCH;
#pragma unroll 4
  for (int t = 0; t < CHUNK; ++t) {
    float bre = p[t * NCH + h];
    float bim = p[t * NCH + 256 + h];
    float nre = lre * sre - lim * sim + bre;
    float nim = lre * sim + lim * sre + bim;
    sre = nre; sim = nim;
  }
  E[c * NCH + h] = sre;
  E[c * NCH + 256 + h] = sim;
}

// ---------------- scan pass 2: Kogge-Stone over chunks, one block per channel
__global__ void scan_pass2(const float* __restrict__ E, const float* __restrict__ lam,
                           float* __restrict__ Sc) {
  int h = blockIdx.x, c = threadIdx.x;  // c in [0, NCHUNKS)
  __shared__ float Ar[NCHUNKS], Ai[NCHUNKS], br[NCHUNKS], bi[NCHUNKS];
  float aR = lam[2 * DHID + h], aI = lam[3 * DHID + h];
  float bR = E[c * NCH + h], bI = E[c * NCH + 256 + h];
  Ar[c] = aR; Ai[c] = aI; br[c] = bR; bi[c] = bI;
  __syncthreads();
  for (int off = 1; off < NCHUNKS; off <<= 1) {
    float paR = 0, paI = 0, pbR = 0, pbI = 0;
    bool has = (c >= off);
    if (has) { paR = Ar[c - off]; paI = Ai[c - off]; pbR = br[c - off]; pbI = bi[c - off]; }
    __syncthreads();
    if (has) {
      float nAR = aR * paR - aI * paI;
      float nAI = aR * paI + aI * paR;
      float nbR = aR * pbR - aI * pbI + bR;
      float nbI = aR * pbI + aI * pbR + bI;
      aR = nAR; aI = nAI; bR = nbR; bI = nbI;
      Ar[c] = aR; Ai[c] = aI; br[c] = bR; bi[c] = bI;
    }
    __syncthreads();
  }
  // incoming carry for chunk c is inclusive state of chunk c-1
  float inR = (c > 0) ? br[c - 1] : 0.f;
  float inI = (c > 0) ? bi[c - 1] : 0.f;
  Sc[c * NCH + h] = inR;
  Sc[c * NCH + 256 + h] = inI;
}

// ---------------- scan pass 3: re-scan with carry, emit h as bf16 ------------
__global__ void scan_pass3(const float* __restrict__ Bu, const float* __restrict__ lam,
                           const float* __restrict__ Sc, bf16_t* __restrict__ Hb) {
  int c = blockIdx.x, h = threadIdx.x;
  float lre = lam[h], lim = lam[DHID + h];
  float sre = Sc[c * NCH + h];
  float sim = Sc[c * NCH + 256 + h];
  const float* p = Bu + (size_t)c * CHUNK * NCH;
  bf16_t* q = Hb + (size_t)c * CHUNK * NCH;
#pragma unroll 4
  for (int t = 0; t < CHUNK; ++t) {
    float bre = p[t * NCH + h];
    float bim = p[t * NCH + 256 + h];
    float nre = lre * sre - lim * sim + bre;
    float nim = lre * sim + lim * sre + bim;
    sre = nre; sim = nim;
    q[t * NCH + h] = (bf16_t)sre;
    q[t * NCH + 256 + h] = (bf16_t)sim;
  }
}

extern "C" void kernel_launch(void* const* d_in, const int* in_sizes, int n_in,
                              void* d_out, int out_size, void* d_ws, size_t ws_size,
                              hipStream_t stream) {
  const float* inputs    = (const float*)d_in[0];
  const float* nu_log    = (const float*)d_in[1];
  const float* theta_log = (const float*)d_in[2];
  const float* gamma_log = (const float*)d_in[3];
  const float* B_re      = (const float*)d_in[4];
  const float* B_im      = (const float*)d_in[5];
  const float* C_re      = (const float*)d_in[6];
  const float* C_im      = (const float*)d_in[7];
  const float* Dvec      = (const float*)d_in[8];
  float* out = (float*)d_out;

  char* w = (char*)d_ws;
  bf16_t* W1 = (bf16_t*)w;  w += (size_t)NCH * DMODEL * 2;    // 256 KB
  bf16_t* W2 = (bf16_t*)w;  w += (size_t)DMODEL * NCH * 2;    // 256 KB
  float* lam = (float*)w;   w += (size_t)4 * DHID * 4;        // 4 KB
  bf16_t* xb = (bf16_t*)w;  w += (size_t)LSEQ * DMODEL * 2;   // 16 MB
  float* Bu  = (float*)w;   w += (size_t)LSEQ * NCH * 4;      // 64 MB
  float* E   = (float*)w;   w += (size_t)NCHUNKS * NCH * 4;   // 512 KB
  float* Sc  = (float*)w;   w += (size_t)NCHUNKS * NCH * 4;   // 512 KB
  bf16_t* Hb = (bf16_t*)w;  w += (size_t)LSEQ * NCH * 2;      // 32 MB

  prep_params<<<1, 256, 0, stream>>>(nu_log, theta_log, lam);
  pack_w1<<<NCH, DMODEL, 0, stream>>>(B_re, B_im, gamma_log, W1);
  pack_w2<<<DMODEL, NCH, 0, stream>>>(C_re, C_im, W2);
  convert_x<<<(LSEQ * DMODEL) / 4 / 256, 256, 0, stream>>>(inputs, xb);

  // GEMM1: Bu[L x 512] = xb[L x 256] @ W1[512 x 256]^T
  gemm_bt<<<dim3(NCH / 128, LSEQ / 128), 256, 0, stream>>>(
      xb, W1, Bu, DMODEL, NCH, nullptr, nullptr, 0);

  scan_pass1<<<NCHUNKS, 256, 0, stream>>>(Bu, lam, E);
  scan_pass2<<<DHID, NCHUNKS, 0, stream>>>(E, lam, Sc);
  scan_pass3<<<NCHUNKS, 256, 0, stream>>>(Bu, lam, Sc, Hb);

  // GEMM2: out[L x 256] = Hb[L x 512] @ W2[256 x 512]^T + inputs * D
  gemm_bt<<<dim3(DMODEL / 128, LSEQ / 128), 256, 0, stream>>>(
      Hb, W2, out, NCH, DMODEL, inputs, Dvec, 1);
}